// Round 18
// baseline (78.168 us; speedup 1.0000x reference)
//
#include <hip/hip_runtime.h>
#include <hip/hip_bf16.h>

#define BSZ   4
#define NTOK  1024
#define DIN   384
#define DST   16
#define MROWS (BSZ * NTOK)     // 4096
#define KDIM  384
#define NM    (MROWS * DIN)    // 1572864 elements per plane

typedef __attribute__((ext_vector_type(8))) short bf16x8;
typedef __attribute__((ext_vector_type(4))) float f32x4;

__device__ __forceinline__ float softplus_f(float z) {
  return (z > 20.0f) ? z : log1pf(expf(z));
}

__device__ __forceinline__ unsigned short f32_to_bf16(float f) {
  unsigned int u = __float_as_uint(f);
  unsigned int rnd = 0x7fffu + ((u >> 16) & 1u);   // round-to-nearest-even
  return (unsigned short)((u + rnd) >> 16);
}

__device__ __forceinline__ float bf16_lo(unsigned int w) { return __uint_as_float(w << 16); }
__device__ __forceinline__ float bf16_hi(unsigned int w) { return __uint_as_float(w & 0xffff0000u); }

// ---------------------------------------------------------------------------
// Kernel W: concat(Wdts|Wdtd|WB|WC|0) f32 -> bf16 rows Wb[832][384]
// ---------------------------------------------------------------------------
__global__ __launch_bounds__(256) void wconv_kernel(
    const float* __restrict__ Wdts, const float* __restrict__ Wdtd,
    const float* __restrict__ WB,   const float* __restrict__ WC,
    unsigned short* __restrict__ Wb)
{
  const int idx8 = (blockIdx.x * 256 + threadIdx.x) * 8;   // 156 blocks
  const int row = idx8 / KDIM;
  const int k   = idx8 % KDIM;
  uint4 o = make_uint4(0u, 0u, 0u, 0u);
  if (row < 800) {
    const float* src;
    if (row < 384)      src = Wdts + (long)row * KDIM + k;
    else if (row < 768) src = Wdtd + (long)(row - 384) * KDIM + k;
    else if (row < 784) src = WB   + (long)(row - 768) * KDIM + k;
    else                src = WC   + (long)(row - 784) * KDIM + k;
    float4 v0 = *(const float4*)src;
    float4 v1 = *(const float4*)(src + 4);
    o.x = (unsigned int)f32_to_bf16(v0.x) | ((unsigned int)f32_to_bf16(v0.y) << 16);
    o.y = (unsigned int)f32_to_bf16(v0.z) | ((unsigned int)f32_to_bf16(v0.w) << 16);
    o.z = (unsigned int)f32_to_bf16(v1.x) | ((unsigned int)f32_to_bf16(v1.y) << 16);
    o.w = (unsigned int)f32_to_bf16(v1.z) | ((unsigned int)f32_to_bf16(v1.w) << 16);
  }
  *(uint4*)&Wb[idx8] = o;
}

// ---------------------------------------------------------------------------
// Kernel 0: x (b,n,d) -> xT (b,d,n) f32  AND  xb (b,n,d) bf16 (for MFMA).
// ---------------------------------------------------------------------------
__global__ __launch_bounds__(256) void xpose_kernel(
    const float* __restrict__ x, float* __restrict__ xT,
    unsigned short* __restrict__ xb)
{
  __shared__ float tile[32][33];
  const int n0 = blockIdx.x * 32;
  const int d0 = blockIdx.y * 32;
  const int b  = blockIdx.z;
  const int tx = threadIdx.x & 31, ty = threadIdx.x >> 5;   // ty 0..7
#pragma unroll
  for (int i = 0; i < 4; ++i) {
    int nn = n0 + ty + i * 8;
    float v = x[(long)(b * NTOK + nn) * DIN + d0 + tx];
    tile[ty + i * 8][tx] = v;
    xb[(long)(b * NTOK + nn) * DIN + d0 + tx] = f32_to_bf16(v);
  }
  __syncthreads();
#pragma unroll
  for (int i = 0; i < 4; ++i) {
    int dd = d0 + ty + i * 8;
    xT[(long)(b * DIN + dd) * NTOK + n0 + tx] = tile[tx][ty + i * 8];
  }
}

// ---------------------------------------------------------------------------
// Kernel 1: full projection GEMM via bf16 MFMA (4096 x 832 x 384), BK=64,
// double-buffered LDS + TWO-ITER-DEEP register prefetch (fully unrolled so
// reg-buffer indices are compile-time): load(it+2) issued at iter it,
// consumed by PSTORE at iter it+1 -> ~600cyc hiding window (was ~270).
//   bn<12 : delta cols -> softplus+clamp, bf16, LDS-transpose, d-major planes
//   bn==12: B/C cols -> f32 TRANSPOSED planes BT/CT[s][4096] (float4 stores)
// ---------------------------------------------------------------------------
__global__ __launch_bounds__(256) void proj_mfma_kernel(
    const unsigned short* __restrict__ xb,   // bf16 x, row-major [4096][384]
    const unsigned short* __restrict__ Wb,   // bf16 W, row-major [832][384]
    const float* __restrict__ bdts, const float* __restrict__ bdtd,
    unsigned short* __restrict__ dsT, unsigned short* __restrict__ ddT,
    float* __restrict__ BT, float* __restrict__ CT)
{
  __shared__ short smem_s[2][2][64 * 72];   // [buf][A|W][64 rows x 72 pad] = 36864 B

  const int t    = threadIdx.x;
  const int bm   = blockIdx.x & 63;         // 64 row tiles
  const int bn   = blockIdx.x >> 6;         // 13 col tiles
  const int row0 = bm * 64;
  const int col0 = bn * 64;                 // 0..831
  const int bat  = row0 >> 10;
  const int n0   = row0 & 1023;

  const int l  = t & 63;
  const int w  = t >> 6;
  const int wr = (w >> 1) * 32;             // wave row base
  const int wc = (w & 1) * 32;              // wave col base
  const int lr = l & 15;
  const int lk = (l >> 4) * 8;              // k offset in frag (bf16)

  const int sr = t >> 2;                    // staging row 0..63
  const int sk = (t & 3) * 16;              // staging k (shorts), 2x uint4

  f32x4 acc[2][2];
  const f32x4 zero = {0.f, 0.f, 0.f, 0.f};
  acc[0][0] = zero; acc[0][1] = zero; acc[1][0] = zero; acc[1][1] = zero;

  uint4 la[2][2], lw[2][2];                 // [set][half]
#define PLOADS(SET, K0)                                                    \
  {                                                                        \
    const unsigned short* ap = &xb[(long)(row0 + sr) * KDIM + (K0) + sk];  \
    const unsigned short* wp = &Wb[(long)(col0 + sr) * KDIM + (K0) + sk];  \
    la[SET][0] = *(const uint4*)ap;  la[SET][1] = *(const uint4*)(ap + 8); \
    lw[SET][0] = *(const uint4*)wp;  lw[SET][1] = *(const uint4*)(wp + 8); \
  }
#define PSTORES(BUF, SET)                                                  \
  {                                                                        \
    *(uint4*)&smem_s[BUF][0][sr * 72 + sk]     = la[SET][0];               \
    *(uint4*)&smem_s[BUF][0][sr * 72 + sk + 8] = la[SET][1];               \
    *(uint4*)&smem_s[BUF][1][sr * 72 + sk]     = lw[SET][0];               \
    *(uint4*)&smem_s[BUF][1][sr * 72 + sk + 8] = lw[SET][1];               \
  }

  PLOADS(0, 0);
  PSTORES(0, 0);
  PLOADS(1, 64);                            // tile 1 in reg set 1

#pragma unroll
  for (int it = 0; it < 6; ++it) {
    const int cur = it & 1;
    __syncthreads();                        // LDS[cur] ready; prev readers done
    if (it + 2 < 6) PLOADS(cur, (it + 2) * 64);   // reg set cur is free now
    const short* Asm = smem_s[cur][0];
    const short* Wsm = smem_s[cur][1];
#pragma unroll
    for (int kh = 0; kh < 2; ++kh) {
      const int ko = kh * 32 + lk;
      bf16x8 a0 = *(const bf16x8*)&Asm[(wr + lr) * 72 + ko];
      bf16x8 a1 = *(const bf16x8*)&Asm[(wr + 16 + lr) * 72 + ko];
      bf16x8 b0 = *(const bf16x8*)&Wsm[(wc + lr) * 72 + ko];
      bf16x8 b1 = *(const bf16x8*)&Wsm[(wc + 16 + lr) * 72 + ko];
      acc[0][0] = __builtin_amdgcn_mfma_f32_16x16x32_bf16(a0, b0, acc[0][0], 0, 0, 0);
      acc[0][1] = __builtin_amdgcn_mfma_f32_16x16x32_bf16(a0, b1, acc[0][1], 0, 0, 0);
      acc[1][0] = __builtin_amdgcn_mfma_f32_16x16x32_bf16(a1, b0, acc[1][0], 0, 0, 0);
      acc[1][1] = __builtin_amdgcn_mfma_f32_16x16x32_bf16(a1, b1, acc[1][1], 0, 0, 0);
    }
    if (it + 1 < 6) PSTORES(cur ^ 1, cur ^ 1);    // vmcnt wait: ~full iter old
  }

  if (bn < 12) {
    const float* bias = (bn < 6) ? bdts : bdtd;
    unsigned short* plane = (bn < 6) ? dsT : ddT;
    const int dbase = (bn < 6) ? col0 : col0 - 384;
    const float bv0 = bias[dbase + wc + lr];
    const float bv1 = bias[dbase + wc + 16 + lr];
    __syncthreads();
    unsigned short* outl = (unsigned short*)smem_s;   // [64 d][72 n] u16
#pragma unroll
    for (int i = 0; i < 2; ++i)
#pragma unroll
      for (int j = 0; j < 2; ++j) {
        const float bb = j ? bv1 : bv0;
        const int cl = wc + j * 16 + lr;
#pragma unroll
        for (int q = 0; q < 4; ++q) {
          const int nl = wr + i * 16 + (l >> 4) * 4 + q;
          float dl = fminf(softplus_f(acc[i][j][q] + bb), 0.15f);
          outl[cl * 72 + nl] = f32_to_bf16(dl);
        }
      }
    __syncthreads();
    const int dl = t >> 2;
    const int seg = t & 3;
    uint4 w0 = *(const uint4*)&outl[dl * 72 + seg * 16];
    uint4 w1 = *(const uint4*)&outl[dl * 72 + seg * 16 + 8];
    long addr = (long)(bat * DIN + dbase + dl) * NTOK + n0 + seg * 16;
    *(uint4*)&plane[addr]     = w0;
    *(uint4*)&plane[addr + 8] = w1;
  } else {
    // B/C epilogue: transposed f32 planes, float4 per (i,j) fragment
#pragma unroll
    for (int i = 0; i < 2; ++i)
#pragma unroll
      for (int j = 0; j < 2; ++j) {
        const int cl = wc + j * 16 + lr;
        const int rowbase = row0 + wr + i * 16 + (l >> 4) * 4;
        if (cl < 16)       *(f32x4*)&BT[(long)cl * MROWS + rowbase] = acc[i][j];
        else if (cl < 32)  *(f32x4*)&CT[(long)(cl - 16) * MROWS + rowbase] = acc[i][j];
      }
  }
#undef PLOADS
#undef PSTORES
}

// ---------------------------------------------------------------------------
// Kernel 2: wave-parallel recurrence, QUARTER-SPLIT. Block = (b,d,squarter):
// 256 thr = 4 waves = 4 s-channels. Lane owns a 4x4 f32 register patch of the
// 32x32 grid; halo via __shfl; no LDS/barriers in k-loop. End: LDS-reduce the
// 4 partials (P[4][1024] = 16 KB) and write a bf16 partial plane yQ[squarter].
// Up to 8 blocks/CU (2048 thr, 128 KB LDS) -> finer residency than r16's 512.
// untranspose sums yQ0..3 and adds the x*D residual.
// NOTE: no 2nd launch_bounds arg (r9/r13: it force-caps VGPR -> spills).
// ---------------------------------------------------------------------------
__global__ __launch_bounds__(256) void ssm_kernel(
    const float* __restrict__ xT,
    const unsigned short* __restrict__ dsT,
    const unsigned short* __restrict__ ddT,
    const float* __restrict__ BT, const float* __restrict__ CT,
    const float* __restrict__ Alog,
    const float* __restrict__ diffraw, const int* __restrict__ Kp,
    unsigned short* __restrict__ yQ0, unsigned short* __restrict__ yQ1,
    unsigned short* __restrict__ yQ2, unsigned short* __restrict__ yQ3)
{
  __shared__ float P[4 * 1024];             // 16384 B partial plane
  const int bid  = blockIdx.x;
  const int sq   = bid & 3;
  const int bd   = bid >> 2;
  const int d = bd % DIN;
  const int b = bd / DIN;
  const int t   = threadIdx.x;              // 0..255
  const int s   = sq * 4 + (t >> 6);        // global state channel
  const int l64 = t & 63;
  const int pr  = l64 >> 3, pc = l64 & 7;   // 8x8 lane grid, 4x4 patch each
  const int K = Kp[0];
  const float dt = 1.0f / (float)K;
  const float Dc = 0.5f / (1.0f + expf(-diffraw[d]));
  const float A  = -log1pf(expf(Alog[d * DST + s]));
  const float dtDc = dt * Dc;
  const long col = (long)(b * DIN + d) * NTOK;
  const long gr0 = (long)b * NTOK;
  const int  c0  = pc * 4;

  float h[16], cA[16], g0[16], a2v[16];
#pragma unroll
  for (int i = 0; i < 4; ++i) {
    const int n = (pr * 4 + i) * 32 + c0;
    float4 xv = *(const float4*)&xT[col + n];
    float4 bv = *(const float4*)&BT[(long)s * MROWS + gr0 + n];
    uint2 dsw = *(const uint2*)&dsT[col + n];
    uint2 ddw = *(const uint2*)&ddT[col + n];
    float dsf[4] = { bf16_lo(dsw.x), bf16_hi(dsw.x), bf16_lo(dsw.y), bf16_hi(dsw.y) };
    float ddf[4] = { bf16_lo(ddw.x), bf16_hi(ddw.x), bf16_lo(ddw.y), bf16_hi(ddw.y) };
    float xa[4] = { xv.x, xv.y, xv.z, xv.w };
    float ba[4] = { bv.x, bv.y, bv.z, bv.w };
#pragma unroll
    for (int j = 0; j < 4; ++j) {
      const int e = i * 4 + j;
      float a1 = dt * dsf[j];
      float a2 = dtDc * ddf[j];
      float h0 = xa[j] * ba[j];
      h[e]   = h0;
      g0[e]  = a1 * h0;
      a2v[e] = a2;
      cA[e]  = fmaf(a1, A, 1.0f) - 4.0f * a2;
    }
  }

  const int lu = (l64 - 8) & 63, ld = (l64 + 8) & 63;
  const int ll = (l64 - 1) & 63, lrr = (l64 + 1) & 63;

  for (int k = 0; k < K; ++k) {
    float up[4], dn[4], lf[4], rt[4];
#pragma unroll
    for (int j = 0; j < 4; ++j) {
      up[j] = __shfl(h[12 + j], lu);        // lane above's bottom row
      dn[j] = __shfl(h[j], ld);             // lane below's top row
      lf[j] = __shfl(h[4 * j + 3], ll);     // left lane's right col
      rt[j] = __shfl(h[4 * j], lrr);        // right lane's left col
    }
#pragma unroll
    for (int j = 0; j < 4; ++j) {           // replicate-pad at grid edges
      up[j] = (pr == 0) ? h[j]          : up[j];
      dn[j] = (pr == 7) ? h[12 + j]     : dn[j];
      lf[j] = (pc == 0) ? h[4 * j]      : lf[j];
      rt[j] = (pc == 7) ? h[4 * j + 3]  : rt[j];
    }
    float hn[16];
#pragma unroll
    for (int i = 0; i < 4; ++i)
#pragma unroll
      for (int j = 0; j < 4; ++j) {
        const int e = i * 4 + j;
        float uv = (i == 0) ? up[j] : h[e - 4];
        float dv = (i == 3) ? dn[j] : h[e + 4];
        float lv = (j == 0) ? lf[i] : h[e - 1];
        float rv = (j == 3) ? rt[i] : h[e + 1];
        float S  = (uv + dv) + (lv + rv);
        hn[e] = fmaf(cA[e], h[e], fmaf(a2v[e], S, g0[e]));
      }
#pragma unroll
    for (int e = 0; e < 16; ++e) h[e] = hn[e];
  }

  // per-s partial y into LDS (wave index = s & 3)
  const int sw = t >> 6;
#pragma unroll
  for (int i = 0; i < 4; ++i) {
    const int n = (pr * 4 + i) * 32 + c0;
    float4 cv = *(const float4*)&CT[(long)s * MROWS + gr0 + n];
    float4 pv;
    pv.x = h[i * 4 + 0] * cv.x;
    pv.y = h[i * 4 + 1] * cv.y;
    pv.z = h[i * 4 + 2] * cv.z;
    pv.w = h[i * 4 + 3] * cv.w;
    *(float4*)&P[sw * 1024 + n] = pv;
  }
  __syncthreads();

  // reduce 4 partials; thread t owns points t, t+256, t+512, t+768
  unsigned short* yQ = (sq == 0) ? yQ0 : (sq == 1) ? yQ1 : (sq == 2) ? yQ2 : yQ3;
#pragma unroll
  for (int j = 0; j < 4; ++j) {
    const int n = t + j * 256;
    float sum = P[n] + P[1024 + n] + P[2048 + n] + P[3072 + n];
    yQ[col + n] = f32_to_bf16(sum);
  }
}

// ---------------------------------------------------------------------------
// Kernel 3: out(b,n,d) = yQ0+yQ1+yQ2+yQ3 + x*D, transposed via LDS tile.
// ---------------------------------------------------------------------------
__global__ __launch_bounds__(256) void untranspose_kernel(
    const unsigned short* __restrict__ yQ0, const unsigned short* __restrict__ yQ1,
    const unsigned short* __restrict__ yQ2, const unsigned short* __restrict__ yQ3,
    const float* __restrict__ xT, const float* __restrict__ Dparam,
    float* __restrict__ out)
{
  __shared__ float tile[32][33];
  const int n0 = blockIdx.x * 32;
  const int d0 = blockIdx.y * 32;
  const int b  = blockIdx.z;
  const int tx = threadIdx.x & 31, ty = threadIdx.x >> 5;
#pragma unroll
  for (int i = 0; i < 4; ++i) {
    int dd = d0 + ty + i * 8;
    long idx = (long)(b * DIN + dd) * NTOK + n0 + tx;
    float v0 = __uint_as_float((unsigned int)yQ0[idx] << 16);
    float v1 = __uint_as_float((unsigned int)yQ1[idx] << 16);
    float v2 = __uint_as_float((unsigned int)yQ2[idx] << 16);
    float v3 = __uint_as_float((unsigned int)yQ3[idx] << 16);
    tile[ty + i * 8][tx] = ((v0 + v1) + (v2 + v3)) + xT[idx] * Dparam[dd];
  }
  __syncthreads();
#pragma unroll
  for (int i = 0; i < 4; ++i) {
    int nn = n0 + ty + i * 8;
    out[(long)(b * NTOK + nn) * DIN + d0 + tx] = tile[tx][ty + i * 8];
  }
}

extern "C" void kernel_launch(void* const* d_in, const int* in_sizes, int n_in,
                              void* d_out, int out_size, void* d_ws, size_t ws_size,
                              hipStream_t stream) {
  const float* x     = (const float*)d_in[0];
  const float* Wdts  = (const float*)d_in[1];
  const float* bdts  = (const float*)d_in[2];
  const float* Wdtd  = (const float*)d_in[3];
  const float* bdtd  = (const float*)d_in[4];
  const float* WB    = (const float*)d_in[5];
  const float* WC    = (const float*)d_in[6];
  const float* Dpar  = (const float*)d_in[7];
  const float* Alog  = (const float*)d_in[8];
  const float* diffr = (const float*)d_in[9];
  const int*   Kst   = (const int*)d_in[10];

  // ws layout (~19.4 MB): BT | CT | xT | yQ0..yQ3 (bf16).  xb+Wb alias the yQ
  // region (dead until ssm writes yQ — stream-ordered).
  float* BT = (float*)d_ws;                        // [16][4096]
  float* CT = BT + (long)DST * MROWS;              // [16][4096]
  float* xT = CT + (long)DST * MROWS;
  unsigned short* yQ0 = (unsigned short*)(xT + NM);   // 4 x NM u16
  unsigned short* yQ1 = yQ0 + NM;
  unsigned short* yQ2 = yQ1 + NM;
  unsigned short* yQ3 = yQ2 + NM;
  unsigned short* xb  = yQ0;                          // alias (pre-ssm)
  unsigned short* Wb  = xb + NM;                      // 832*384 bf16

  // d_out scratch: bf16 delta planes between proj and ssm
  unsigned short* dsT = (unsigned short*)d_out;
  unsigned short* ddT = dsT + NM;

  wconv_kernel<<<dim3(156), dim3(256), 0, stream>>>(Wdts, Wdtd, WB, WC, Wb);

  xpose_kernel<<<dim3(NTOK / 32, DIN / 32, BSZ), dim3(256), 0, stream>>>(x, xT, xb);

  proj_mfma_kernel<<<dim3(64 * 13), dim3(256), 0, stream>>>(
      xb, Wb, bdts, bdtd, dsT, ddT, BT, CT);

  ssm_kernel<<<dim3(BSZ * DIN * 4), dim3(256), 0, stream>>>(
      xT, dsT, ddT, BT, CT, Alog, diffr, Kst, yQ0, yQ1, yQ2, yQ3);

  untranspose_kernel<<<dim3(NTOK / 32, DIN / 32, BSZ), dim3(256), 0, stream>>>(
      yQ0, yQ1, yQ2, yQ3, xT, Dpar, (float*)d_out);
}

// Round 19
// 66.843 us; speedup vs baseline: 1.1694x; 1.1694x over previous
//
#include <hip/hip_runtime.h>
#include <hip/hip_bf16.h>

#define BSZ   4
#define NTOK  1024
#define DIN   384
#define DST   16
#define MROWS (BSZ * NTOK)     // 4096
#define KDIM  384
#define NM    (MROWS * DIN)    // 1572864 elements per plane

typedef __attribute__((ext_vector_type(8))) short bf16x8;
typedef __attribute__((ext_vector_type(4))) float f32x4;

__device__ __forceinline__ float softplus_f(float z) {
  return (z > 20.0f) ? z : log1pf(expf(z));
}

__device__ __forceinline__ unsigned short f32_to_bf16(float f) {
  unsigned int u = __float_as_uint(f);
  unsigned int rnd = 0x7fffu + ((u >> 16) & 1u);   // round-to-nearest-even
  return (unsigned short)((u + rnd) >> 16);
}

__device__ __forceinline__ float bf16_lo(unsigned int w) { return __uint_as_float(w << 16); }
__device__ __forceinline__ float bf16_hi(unsigned int w) { return __uint_as_float(w & 0xffff0000u); }

// ---------------------------------------------------------------------------
// Kernel W: concat(Wdts|Wdtd|WB|WC|0) f32 -> bf16 rows Wb[832][384]
// ---------------------------------------------------------------------------
__global__ __launch_bounds__(256) void wconv_kernel(
    const float* __restrict__ Wdts, const float* __restrict__ Wdtd,
    const float* __restrict__ WB,   const float* __restrict__ WC,
    unsigned short* __restrict__ Wb)
{
  const int idx8 = (blockIdx.x * 256 + threadIdx.x) * 8;   // 156 blocks
  const int row = idx8 / KDIM;
  const int k   = idx8 % KDIM;
  uint4 o = make_uint4(0u, 0u, 0u, 0u);
  if (row < 800) {
    const float* src;
    if (row < 384)      src = Wdts + (long)row * KDIM + k;
    else if (row < 768) src = Wdtd + (long)(row - 384) * KDIM + k;
    else if (row < 784) src = WB   + (long)(row - 768) * KDIM + k;
    else                src = WC   + (long)(row - 784) * KDIM + k;
    float4 v0 = *(const float4*)src;
    float4 v1 = *(const float4*)(src + 4);
    o.x = (unsigned int)f32_to_bf16(v0.x) | ((unsigned int)f32_to_bf16(v0.y) << 16);
    o.y = (unsigned int)f32_to_bf16(v0.z) | ((unsigned int)f32_to_bf16(v0.w) << 16);
    o.z = (unsigned int)f32_to_bf16(v1.x) | ((unsigned int)f32_to_bf16(v1.y) << 16);
    o.w = (unsigned int)f32_to_bf16(v1.z) | ((unsigned int)f32_to_bf16(v1.w) << 16);
  }
  *(uint4*)&Wb[idx8] = o;
}

// ---------------------------------------------------------------------------
// Kernel 0: x (b,n,d) -> xT (b,d,n) f32  AND  xb (b,n,d) bf16 (for MFMA).
// ---------------------------------------------------------------------------
__global__ __launch_bounds__(256) void xpose_kernel(
    const float* __restrict__ x, float* __restrict__ xT,
    unsigned short* __restrict__ xb)
{
  __shared__ float tile[32][33];
  const int n0 = blockIdx.x * 32;
  const int d0 = blockIdx.y * 32;
  const int b  = blockIdx.z;
  const int tx = threadIdx.x & 31, ty = threadIdx.x >> 5;   // ty 0..7
#pragma unroll
  for (int i = 0; i < 4; ++i) {
    int nn = n0 + ty + i * 8;
    float v = x[(long)(b * NTOK + nn) * DIN + d0 + tx];
    tile[ty + i * 8][tx] = v;
    xb[(long)(b * NTOK + nn) * DIN + d0 + tx] = f32_to_bf16(v);
  }
  __syncthreads();
#pragma unroll
  for (int i = 0; i < 4; ++i) {
    int dd = d0 + ty + i * 8;
    xT[(long)(b * DIN + dd) * NTOK + n0 + tx] = tile[tx][ty + i * 8];
  }
}

// ---------------------------------------------------------------------------
// Kernel 1: full projection GEMM via bf16 MFMA (4096 x 832 x 384), BK=64,
// double-buffered LDS, ONE reg prefetch set, loads issued AFTER the barrier
// (round-16 pipeline — round-18's 2-deep reg prefetch made hipcc reschedule
// loads next to stores, VGPR 52, MfmaUtil 2%, 45us: REVERTED).
//   bn<12 : delta cols -> softplus+clamp, bf16, LDS-transpose, d-major planes
//   bn==12: B/C cols -> f32 TRANSPOSED planes BT/CT[s][4096] (float4 stores)
// ---------------------------------------------------------------------------
__global__ __launch_bounds__(256) void proj_mfma_kernel(
    const unsigned short* __restrict__ xb,   // bf16 x, row-major [4096][384]
    const unsigned short* __restrict__ Wb,   // bf16 W, row-major [832][384]
    const float* __restrict__ bdts, const float* __restrict__ bdtd,
    unsigned short* __restrict__ dsT, unsigned short* __restrict__ ddT,
    float* __restrict__ BT, float* __restrict__ CT)
{
  __shared__ short smem_s[2][2][64 * 72];   // [buf][A|W][64 rows x 72 pad] = 36864 B

  const int t    = threadIdx.x;
  const int bm   = blockIdx.x & 63;         // 64 row tiles
  const int bn   = blockIdx.x >> 6;         // 13 col tiles
  const int row0 = bm * 64;
  const int col0 = bn * 64;                 // 0..831
  const int bat  = row0 >> 10;
  const int n0   = row0 & 1023;

  const int l  = t & 63;
  const int w  = t >> 6;
  const int wr = (w >> 1) * 32;             // wave row base
  const int wc = (w & 1) * 32;              // wave col base
  const int lr = l & 15;
  const int lk = (l >> 4) * 8;              // k offset in frag (bf16)

  const int sr = t >> 2;                    // staging row 0..63
  const int sk = (t & 3) * 16;              // staging k (shorts), 2x uint4

  f32x4 acc[2][2];
  const f32x4 zero = {0.f, 0.f, 0.f, 0.f};
  acc[0][0] = zero; acc[0][1] = zero; acc[1][0] = zero; acc[1][1] = zero;

  uint4 la0, la1, lw0, lw1;
#define PLOAD(K0)                                                          \
  {                                                                        \
    const unsigned short* ap = &xb[(long)(row0 + sr) * KDIM + (K0) + sk];  \
    const unsigned short* wp = &Wb[(long)(col0 + sr) * KDIM + (K0) + sk];  \
    la0 = *(const uint4*)ap;  la1 = *(const uint4*)(ap + 8);               \
    lw0 = *(const uint4*)wp;  lw1 = *(const uint4*)(wp + 8);               \
  }
#define PSTORE(BUF)                                                        \
  {                                                                        \
    *(uint4*)&smem_s[BUF][0][sr * 72 + sk]     = la0;                      \
    *(uint4*)&smem_s[BUF][0][sr * 72 + sk + 8] = la1;                      \
    *(uint4*)&smem_s[BUF][1][sr * 72 + sk]     = lw0;                      \
    *(uint4*)&smem_s[BUF][1][sr * 72 + sk + 8] = lw1;                      \
  }

  PLOAD(0);
  PSTORE(0);

  for (int it = 0; it < 6; ++it) {
    const int cur = it & 1;
    __syncthreads();                        // lds[cur] visible; lds[cur^1] readers done
    if (it + 1 < 6) PLOAD((it + 1) * 64);   // in flight across MFMA + ds_write
    const short* Asm = smem_s[cur][0];
    const short* Wsm = smem_s[cur][1];
#pragma unroll
    for (int kh = 0; kh < 2; ++kh) {
      const int ko = kh * 32 + lk;
      bf16x8 a0 = *(const bf16x8*)&Asm[(wr + lr) * 72 + ko];
      bf16x8 a1 = *(const bf16x8*)&Asm[(wr + 16 + lr) * 72 + ko];
      bf16x8 b0 = *(const bf16x8*)&Wsm[(wc + lr) * 72 + ko];
      bf16x8 b1 = *(const bf16x8*)&Wsm[(wc + 16 + lr) * 72 + ko];
      acc[0][0] = __builtin_amdgcn_mfma_f32_16x16x32_bf16(a0, b0, acc[0][0], 0, 0, 0);
      acc[0][1] = __builtin_amdgcn_mfma_f32_16x16x32_bf16(a0, b1, acc[0][1], 0, 0, 0);
      acc[1][0] = __builtin_amdgcn_mfma_f32_16x16x32_bf16(a1, b0, acc[1][0], 0, 0, 0);
      acc[1][1] = __builtin_amdgcn_mfma_f32_16x16x32_bf16(a1, b1, acc[1][1], 0, 0, 0);
    }
    if (it + 1 < 6) PSTORE(cur ^ 1);        // vmcnt wait lands here, after MFMA
  }

  if (bn < 12) {
    const float* bias = (bn < 6) ? bdts : bdtd;
    unsigned short* plane = (bn < 6) ? dsT : ddT;
    const int dbase = (bn < 6) ? col0 : col0 - 384;
    const float bv0 = bias[dbase + wc + lr];
    const float bv1 = bias[dbase + wc + 16 + lr];
    __syncthreads();
    unsigned short* outl = (unsigned short*)smem_s;   // [64 d][72 n] u16
#pragma unroll
    for (int i = 0; i < 2; ++i)
#pragma unroll
      for (int j = 0; j < 2; ++j) {
        const float bb = j ? bv1 : bv0;
        const int cl = wc + j * 16 + lr;
#pragma unroll
        for (int q = 0; q < 4; ++q) {
          const int nl = wr + i * 16 + (l >> 4) * 4 + q;
          float dl = fminf(softplus_f(acc[i][j][q] + bb), 0.15f);
          outl[cl * 72 + nl] = f32_to_bf16(dl);
        }
      }
    __syncthreads();
    const int dl = t >> 2;
    const int seg = t & 3;
    uint4 w0 = *(const uint4*)&outl[dl * 72 + seg * 16];
    uint4 w1 = *(const uint4*)&outl[dl * 72 + seg * 16 + 8];
    long addr = (long)(bat * DIN + dbase + dl) * NTOK + n0 + seg * 16;
    *(uint4*)&plane[addr]     = w0;
    *(uint4*)&plane[addr + 8] = w1;
  } else {
    // B/C epilogue: transposed f32 planes, float4 per (i,j) fragment
#pragma unroll
    for (int i = 0; i < 2; ++i)
#pragma unroll
      for (int j = 0; j < 2; ++j) {
        const int cl = wc + j * 16 + lr;
        const int rowbase = row0 + wr + i * 16 + (l >> 4) * 4;
        if (cl < 16)       *(f32x4*)&BT[(long)cl * MROWS + rowbase] = acc[i][j];
        else if (cl < 32)  *(f32x4*)&CT[(long)(cl - 16) * MROWS + rowbase] = acc[i][j];
      }
  }
#undef PLOAD
#undef PSTORE
}

// ---------------------------------------------------------------------------
// Kernel 2: wave-parallel recurrence, QUARTER-SPLIT. Block = (b,d,squarter):
// 256 thr = 4 waves = 4 s-channels. Lane owns a 4x4 f32 register patch of the
// 32x32 grid; halo via __shfl; no LDS/barriers in k-loop. End: LDS-reduce the
// 4 partials (P[4][1024] = 16 KB) and write a bf16 partial plane yQ[squarter].
// Up to 8 blocks/CU -> finer residency than the 512-thr half-split (r16).
// untranspose sums yQ0..3 and adds the x*D residual.
// NOTE: no 2nd launch_bounds arg (r9/r13: it force-caps VGPR -> spills).
// ---------------------------------------------------------------------------
__global__ __launch_bounds__(256) void ssm_kernel(
    const float* __restrict__ xT,
    const unsigned short* __restrict__ dsT,
    const unsigned short* __restrict__ ddT,
    const float* __restrict__ BT, const float* __restrict__ CT,
    const float* __restrict__ Alog,
    const float* __restrict__ diffraw, const int* __restrict__ Kp,
    unsigned short* __restrict__ yQ0, unsigned short* __restrict__ yQ1,
    unsigned short* __restrict__ yQ2, unsigned short* __restrict__ yQ3)
{
  __shared__ float P[4 * 1024];             // 16384 B partial plane
  const int bid  = blockIdx.x;
  const int sq   = bid & 3;
  const int bd   = bid >> 2;
  const int d = bd % DIN;
  const int b = bd / DIN;
  const int t   = threadIdx.x;              // 0..255
  const int s   = sq * 4 + (t >> 6);        // global state channel
  const int l64 = t & 63;
  const int pr  = l64 >> 3, pc = l64 & 7;   // 8x8 lane grid, 4x4 patch each
  const int K = Kp[0];
  const float dt = 1.0f / (float)K;
  const float Dc = 0.5f / (1.0f + expf(-diffraw[d]));
  const float A  = -log1pf(expf(Alog[d * DST + s]));
  const float dtDc = dt * Dc;
  const long col = (long)(b * DIN + d) * NTOK;
  const long gr0 = (long)b * NTOK;
  const int  c0  = pc * 4;

  float h[16], cA[16], g0[16], a2v[16];
#pragma unroll
  for (int i = 0; i < 4; ++i) {
    const int n = (pr * 4 + i) * 32 + c0;
    float4 xv = *(const float4*)&xT[col + n];
    float4 bv = *(const float4*)&BT[(long)s * MROWS + gr0 + n];
    uint2 dsw = *(const uint2*)&dsT[col + n];
    uint2 ddw = *(const uint2*)&ddT[col + n];
    float dsf[4] = { bf16_lo(dsw.x), bf16_hi(dsw.x), bf16_lo(dsw.y), bf16_hi(dsw.y) };
    float ddf[4] = { bf16_lo(ddw.x), bf16_hi(ddw.x), bf16_lo(ddw.y), bf16_hi(ddw.y) };
    float xa[4] = { xv.x, xv.y, xv.z, xv.w };
    float ba[4] = { bv.x, bv.y, bv.z, bv.w };
#pragma unroll
    for (int j = 0; j < 4; ++j) {
      const int e = i * 4 + j;
      float a1 = dt * dsf[j];
      float a2 = dtDc * ddf[j];
      float h0 = xa[j] * ba[j];
      h[e]   = h0;
      g0[e]  = a1 * h0;
      a2v[e] = a2;
      cA[e]  = fmaf(a1, A, 1.0f) - 4.0f * a2;
    }
  }

  const int lu = (l64 - 8) & 63, ld = (l64 + 8) & 63;
  const int ll = (l64 - 1) & 63, lrr = (l64 + 1) & 63;

  for (int k = 0; k < K; ++k) {
    float up[4], dn[4], lf[4], rt[4];
#pragma unroll
    for (int j = 0; j < 4; ++j) {
      up[j] = __shfl(h[12 + j], lu);        // lane above's bottom row
      dn[j] = __shfl(h[j], ld);             // lane below's top row
      lf[j] = __shfl(h[4 * j + 3], ll);     // left lane's right col
      rt[j] = __shfl(h[4 * j], lrr);        // right lane's left col
    }
#pragma unroll
    for (int j = 0; j < 4; ++j) {           // replicate-pad at grid edges
      up[j] = (pr == 0) ? h[j]          : up[j];
      dn[j] = (pr == 7) ? h[12 + j]     : dn[j];
      lf[j] = (pc == 0) ? h[4 * j]      : lf[j];
      rt[j] = (pc == 7) ? h[4 * j + 3]  : rt[j];
    }
    float hn[16];
#pragma unroll
    for (int i = 0; i < 4; ++i)
#pragma unroll
      for (int j = 0; j < 4; ++j) {
        const int e = i * 4 + j;
        float uv = (i == 0) ? up[j] : h[e - 4];
        float dv = (i == 3) ? dn[j] : h[e + 4];
        float lv = (j == 0) ? lf[i] : h[e - 1];
        float rv = (j == 3) ? rt[i] : h[e + 1];
        float S  = (uv + dv) + (lv + rv);
        hn[e] = fmaf(cA[e], h[e], fmaf(a2v[e], S, g0[e]));
      }
#pragma unroll
    for (int e = 0; e < 16; ++e) h[e] = hn[e];
  }

  // per-s partial y into LDS (wave index = s & 3)
  const int sw = t >> 6;
#pragma unroll
  for (int i = 0; i < 4; ++i) {
    const int n = (pr * 4 + i) * 32 + c0;
    float4 cv = *(const float4*)&CT[(long)s * MROWS + gr0 + n];
    float4 pv;
    pv.x = h[i * 4 + 0] * cv.x;
    pv.y = h[i * 4 + 1] * cv.y;
    pv.z = h[i * 4 + 2] * cv.z;
    pv.w = h[i * 4 + 3] * cv.w;
    *(float4*)&P[sw * 1024 + n] = pv;
  }
  __syncthreads();

  // reduce 4 partials; thread t owns points t, t+256, t+512, t+768
  unsigned short* yQ = (sq == 0) ? yQ0 : (sq == 1) ? yQ1 : (sq == 2) ? yQ2 : yQ3;
#pragma unroll
  for (int j = 0; j < 4; ++j) {
    const int n = t + j * 256;
    float sum = P[n] + P[1024 + n] + P[2048 + n] + P[3072 + n];
    yQ[col + n] = f32_to_bf16(sum);
  }
}

// ---------------------------------------------------------------------------
// Kernel 3: out(b,n,d) = yQ0+yQ1+yQ2+yQ3 + x*D, transposed via LDS tile.
// ---------------------------------------------------------------------------
__global__ __launch_bounds__(256) void untranspose_kernel(
    const unsigned short* __restrict__ yQ0, const unsigned short* __restrict__ yQ1,
    const unsigned short* __restrict__ yQ2, const unsigned short* __restrict__ yQ3,
    const float* __restrict__ xT, const float* __restrict__ Dparam,
    float* __restrict__ out)
{
  __shared__ float tile[32][33];
  const int n0 = blockIdx.x * 32;
  const int d0 = blockIdx.y * 32;
  const int b  = blockIdx.z;
  const int tx = threadIdx.x & 31, ty = threadIdx.x >> 5;
#pragma unroll
  for (int i = 0; i < 4; ++i) {
    int dd = d0 + ty + i * 8;
    long idx = (long)(b * DIN + dd) * NTOK + n0 + tx;
    float v0 = __uint_as_float((unsigned int)yQ0[idx] << 16);
    float v1 = __uint_as_float((unsigned int)yQ1[idx] << 16);
    float v2 = __uint_as_float((unsigned int)yQ2[idx] << 16);
    float v3 = __uint_as_float((unsigned int)yQ3[idx] << 16);
    tile[ty + i * 8][tx] = ((v0 + v1) + (v2 + v3)) + xT[idx] * Dparam[dd];
  }
  __syncthreads();
#pragma unroll
  for (int i = 0; i < 4; ++i) {
    int nn = n0 + ty + i * 8;
    out[(long)(b * NTOK + nn) * DIN + d0 + tx] = tile[tx][ty + i * 8];
  }
}

extern "C" void kernel_launch(void* const* d_in, const int* in_sizes, int n_in,
                              void* d_out, int out_size, void* d_ws, size_t ws_size,
                              hipStream_t stream) {
  const float* x     = (const float*)d_in[0];
  const float* Wdts  = (const float*)d_in[1];
  const float* bdts  = (const float*)d_in[2];
  const float* Wdtd  = (const float*)d_in[3];
  const float* bdtd  = (const float*)d_in[4];
  const float* WB    = (const float*)d_in[5];
  const float* WC    = (const float*)d_in[6];
  const float* Dpar  = (const float*)d_in[7];
  const float* Alog  = (const float*)d_in[8];
  const float* diffr = (const float*)d_in[9];
  const int*   Kst   = (const int*)d_in[10];

  // ws layout (~19.4 MB): BT | CT | xT | yQ0..yQ3 (bf16).  xb+Wb alias the yQ
  // region (dead until ssm writes yQ — stream-ordered).
  float* BT = (float*)d_ws;                        // [16][4096]
  float* CT = BT + (long)DST * MROWS;              // [16][4096]
  float* xT = CT + (long)DST * MROWS;
  unsigned short* yQ0 = (unsigned short*)(xT + NM);   // 4 x NM u16
  unsigned short* yQ1 = yQ0 + NM;
  unsigned short* yQ2 = yQ1 + NM;
  unsigned short* yQ3 = yQ2 + NM;
  unsigned short* xb  = yQ0;                          // alias (pre-ssm)
  unsigned short* Wb  = xb + NM;                      // 832*384 bf16

  // d_out scratch: bf16 delta planes between proj and ssm
  unsigned short* dsT = (unsigned short*)d_out;
  unsigned short* ddT = dsT + NM;

  wconv_kernel<<<dim3(156), dim3(256), 0, stream>>>(Wdts, Wdtd, WB, WC, Wb);

  xpose_kernel<<<dim3(NTOK / 32, DIN / 32, BSZ), dim3(256), 0, stream>>>(x, xT, xb);

  proj_mfma_kernel<<<dim3(64 * 13), dim3(256), 0, stream>>>(
      xb, Wb, bdts, bdtd, dsT, ddT, BT, CT);

  ssm_kernel<<<dim3(BSZ * DIN * 4), dim3(256), 0, stream>>>(
      xT, dsT, ddT, BT, CT, Alog, diffr, Kst, yQ0, yQ1, yQ2, yQ3);

  untranspose_kernel<<<dim3(NTOK / 32, DIN / 32, BSZ), dim3(256), 0, stream>>>(
      yQ0, yQ1, yQ2, yQ3, xT, Dpar, (float*)d_out);
}

// Round 20
// 63.721 us; speedup vs baseline: 1.2267x; 1.0490x over previous
//
#include <hip/hip_runtime.h>
#include <hip/hip_bf16.h>

#define BSZ   4
#define NTOK  1024
#define DIN   384
#define DST   16
#define MROWS (BSZ * NTOK)     // 4096
#define KDIM  384
#define NM    (MROWS * DIN)    // 1572864 elements per plane

typedef __attribute__((ext_vector_type(8))) short bf16x8;
typedef __attribute__((ext_vector_type(4))) float f32x4;

__device__ __forceinline__ float softplus_f(float z) {
  return (z > 20.0f) ? z : log1pf(expf(z));
}

__device__ __forceinline__ unsigned short f32_to_bf16(float f) {
  unsigned int u = __float_as_uint(f);
  unsigned int rnd = 0x7fffu + ((u >> 16) & 1u);   // round-to-nearest-even
  return (unsigned short)((u + rnd) >> 16);
}

__device__ __forceinline__ float bf16_lo(unsigned int w) { return __uint_as_float(w << 16); }
__device__ __forceinline__ float bf16_hi(unsigned int w) { return __uint_as_float(w & 0xffff0000u); }

// ---------------------------------------------------------------------------
// Kernel 0 (fused prep): z<4 -> x (b,n,d) -> xT f32 + xb bf16;
//                        z==4 -> concat(Wdts|Wdtd|WB|WC|0) f32 -> bf16 Wb[832][384]
// ---------------------------------------------------------------------------
__global__ __launch_bounds__(256) void prep_kernel(
    const float* __restrict__ x, float* __restrict__ xT,
    unsigned short* __restrict__ xb,
    const float* __restrict__ Wdts, const float* __restrict__ Wdtd,
    const float* __restrict__ WB,   const float* __restrict__ WC,
    unsigned short* __restrict__ Wb)
{
  if (blockIdx.z == 4) {
    const int lin = blockIdx.y * 32 + blockIdx.x;    // 0..383, use 0..155
    if (lin >= 156) return;
    const int idx8 = (lin * 256 + threadIdx.x) * 8;
    const int row = idx8 / KDIM;
    const int k   = idx8 % KDIM;
    uint4 o = make_uint4(0u, 0u, 0u, 0u);
    if (row < 800) {
      const float* src;
      if (row < 384)      src = Wdts + (long)row * KDIM + k;
      else if (row < 768) src = Wdtd + (long)(row - 384) * KDIM + k;
      else if (row < 784) src = WB   + (long)(row - 768) * KDIM + k;
      else                src = WC   + (long)(row - 784) * KDIM + k;
      float4 v0 = *(const float4*)src;
      float4 v1 = *(const float4*)(src + 4);
      o.x = (unsigned int)f32_to_bf16(v0.x) | ((unsigned int)f32_to_bf16(v0.y) << 16);
      o.y = (unsigned int)f32_to_bf16(v0.z) | ((unsigned int)f32_to_bf16(v0.w) << 16);
      o.z = (unsigned int)f32_to_bf16(v1.x) | ((unsigned int)f32_to_bf16(v1.y) << 16);
      o.w = (unsigned int)f32_to_bf16(v1.z) | ((unsigned int)f32_to_bf16(v1.w) << 16);
    }
    *(uint4*)&Wb[idx8] = o;
    return;
  }
  __shared__ float tile[32][33];
  const int n0 = blockIdx.x * 32;
  const int d0 = blockIdx.y * 32;
  const int b  = blockIdx.z;
  const int tx = threadIdx.x & 31, ty = threadIdx.x >> 5;   // ty 0..7
#pragma unroll
  for (int i = 0; i < 4; ++i) {
    int nn = n0 + ty + i * 8;
    float v = x[(long)(b * NTOK + nn) * DIN + d0 + tx];
    tile[ty + i * 8][tx] = v;
    xb[(long)(b * NTOK + nn) * DIN + d0 + tx] = f32_to_bf16(v);
  }
  __syncthreads();
#pragma unroll
  for (int i = 0; i < 4; ++i) {
    int dd = d0 + ty + i * 8;
    xT[(long)(b * DIN + dd) * NTOK + n0 + tx] = tile[tx][ty + i * 8];
  }
}

// ---------------------------------------------------------------------------
// Kernel 1: full projection GEMM via bf16 MFMA (4096 x 832 x 384), BK=64,
// double-buffered LDS, ONE reg prefetch set, loads issued AFTER the barrier
// (round-19-proven pipeline; 2-deep reg prefetch regressed — r18, VGPR 52).
//   bn<12 : delta cols -> softplus+clamp, bf16, LDS-transpose, d-major planes
//   bn==12: B/C cols -> f32 TRANSPOSED planes BT/CT[s][4096] (float4 stores)
// ---------------------------------------------------------------------------
__global__ __launch_bounds__(256) void proj_mfma_kernel(
    const unsigned short* __restrict__ xb,   // bf16 x, row-major [4096][384]
    const unsigned short* __restrict__ Wb,   // bf16 W, row-major [832][384]
    const float* __restrict__ bdts, const float* __restrict__ bdtd,
    unsigned short* __restrict__ dsT, unsigned short* __restrict__ ddT,
    float* __restrict__ BT, float* __restrict__ CT)
{
  __shared__ short smem_s[2][2][64 * 72];   // [buf][A|W][64 rows x 72 pad] = 36864 B

  const int t    = threadIdx.x;
  const int bm   = blockIdx.x & 63;         // 64 row tiles
  const int bn   = blockIdx.x >> 6;         // 13 col tiles
  const int row0 = bm * 64;
  const int col0 = bn * 64;                 // 0..831
  const int bat  = row0 >> 10;
  const int n0   = row0 & 1023;

  const int l  = t & 63;
  const int w  = t >> 6;
  const int wr = (w >> 1) * 32;             // wave row base
  const int wc = (w & 1) * 32;              // wave col base
  const int lr = l & 15;
  const int lk = (l >> 4) * 8;              // k offset in frag (bf16)

  const int sr = t >> 2;                    // staging row 0..63
  const int sk = (t & 3) * 16;              // staging k (shorts), 2x uint4

  f32x4 acc[2][2];
  const f32x4 zero = {0.f, 0.f, 0.f, 0.f};
  acc[0][0] = zero; acc[0][1] = zero; acc[1][0] = zero; acc[1][1] = zero;

  uint4 la0, la1, lw0, lw1;
#define PLOAD(K0)                                                          \
  {                                                                        \
    const unsigned short* ap = &xb[(long)(row0 + sr) * KDIM + (K0) + sk];  \
    const unsigned short* wp = &Wb[(long)(col0 + sr) * KDIM + (K0) + sk];  \
    la0 = *(const uint4*)ap;  la1 = *(const uint4*)(ap + 8);               \
    lw0 = *(const uint4*)wp;  lw1 = *(const uint4*)(wp + 8);               \
  }
#define PSTORE(BUF)                                                        \
  {                                                                        \
    *(uint4*)&smem_s[BUF][0][sr * 72 + sk]     = la0;                      \
    *(uint4*)&smem_s[BUF][0][sr * 72 + sk + 8] = la1;                      \
    *(uint4*)&smem_s[BUF][1][sr * 72 + sk]     = lw0;                      \
    *(uint4*)&smem_s[BUF][1][sr * 72 + sk + 8] = lw1;                      \
  }

  PLOAD(0);
  PSTORE(0);

  for (int it = 0; it < 6; ++it) {
    const int cur = it & 1;
    __syncthreads();                        // lds[cur] visible; lds[cur^1] readers done
    if (it + 1 < 6) PLOAD((it + 1) * 64);   // in flight across MFMA + ds_write
    const short* Asm = smem_s[cur][0];
    const short* Wsm = smem_s[cur][1];
#pragma unroll
    for (int kh = 0; kh < 2; ++kh) {
      const int ko = kh * 32 + lk;
      bf16x8 a0 = *(const bf16x8*)&Asm[(wr + lr) * 72 + ko];
      bf16x8 a1 = *(const bf16x8*)&Asm[(wr + 16 + lr) * 72 + ko];
      bf16x8 b0 = *(const bf16x8*)&Wsm[(wc + lr) * 72 + ko];
      bf16x8 b1 = *(const bf16x8*)&Wsm[(wc + 16 + lr) * 72 + ko];
      acc[0][0] = __builtin_amdgcn_mfma_f32_16x16x32_bf16(a0, b0, acc[0][0], 0, 0, 0);
      acc[0][1] = __builtin_amdgcn_mfma_f32_16x16x32_bf16(a0, b1, acc[0][1], 0, 0, 0);
      acc[1][0] = __builtin_amdgcn_mfma_f32_16x16x32_bf16(a1, b0, acc[1][0], 0, 0, 0);
      acc[1][1] = __builtin_amdgcn_mfma_f32_16x16x32_bf16(a1, b1, acc[1][1], 0, 0, 0);
    }
    if (it + 1 < 6) PSTORE(cur ^ 1);        // vmcnt wait lands here, after MFMA
  }

  if (bn < 12) {
    const float* bias = (bn < 6) ? bdts : bdtd;
    unsigned short* plane = (bn < 6) ? dsT : ddT;
    const int dbase = (bn < 6) ? col0 : col0 - 384;
    const float bv0 = bias[dbase + wc + lr];
    const float bv1 = bias[dbase + wc + 16 + lr];
    __syncthreads();
    unsigned short* outl = (unsigned short*)smem_s;   // [64 d][72 n] u16
#pragma unroll
    for (int i = 0; i < 2; ++i)
#pragma unroll
      for (int j = 0; j < 2; ++j) {
        const float bb = j ? bv1 : bv0;
        const int cl = wc + j * 16 + lr;
#pragma unroll
        for (int q = 0; q < 4; ++q) {
          const int nl = wr + i * 16 + (l >> 4) * 4 + q;
          float dl = fminf(softplus_f(acc[i][j][q] + bb), 0.15f);
          outl[cl * 72 + nl] = f32_to_bf16(dl);
        }
      }
    __syncthreads();
    const int dl = t >> 2;
    const int seg = t & 3;
    uint4 w0 = *(const uint4*)&outl[dl * 72 + seg * 16];
    uint4 w1 = *(const uint4*)&outl[dl * 72 + seg * 16 + 8];
    long addr = (long)(bat * DIN + dbase + dl) * NTOK + n0 + seg * 16;
    *(uint4*)&plane[addr]     = w0;
    *(uint4*)&plane[addr + 8] = w1;
  } else {
    // B/C epilogue: transposed f32 planes, float4 per (i,j) fragment
#pragma unroll
    for (int i = 0; i < 2; ++i)
#pragma unroll
      for (int j = 0; j < 2; ++j) {
        const int cl = wc + j * 16 + lr;
        const int rowbase = row0 + wr + i * 16 + (l >> 4) * 4;
        if (cl < 16)       *(f32x4*)&BT[(long)cl * MROWS + rowbase] = acc[i][j];
        else if (cl < 32)  *(f32x4*)&CT[(long)(cl - 16) * MROWS + rowbase] = acc[i][j];
      }
  }
#undef PLOAD
#undef PSTORE
}

// ---------------------------------------------------------------------------
// Kernel 2: wave-parallel recurrence, QUARTER-SPLIT, sq-MAJOR grid:
//   sq = bid/1536, bd = bid%1536 -> the 4 sq-partners of a (b,d) are 1536
//   apart (same XCD under bid%8 round-robin) -> shared L2 for xT/ds/dd cols.
// 256 thr = 4 waves = 4 s-channels; lane owns a 4x4 f32 register patch;
// halo via __shfl; CT prefetched at START (consumed only after k-loop;
// +16 VGPR targets the 64-VGPR/8-wave boundary exactly).
// NOTE: no 2nd launch_bounds arg (r9/r13: it force-caps VGPR -> spills).
// ---------------------------------------------------------------------------
__global__ __launch_bounds__(256) void ssm_kernel(
    const float* __restrict__ xT,
    const unsigned short* __restrict__ dsT,
    const unsigned short* __restrict__ ddT,
    const float* __restrict__ BT, const float* __restrict__ CT,
    const float* __restrict__ Alog,
    const float* __restrict__ diffraw, const int* __restrict__ Kp,
    unsigned short* __restrict__ yQ0, unsigned short* __restrict__ yQ1,
    unsigned short* __restrict__ yQ2, unsigned short* __restrict__ yQ3)
{
  __shared__ float P[4 * 1024];             // 16384 B partial plane
  const int bid  = blockIdx.x;
  const int sq   = bid / (BSZ * DIN);       // sq-major (XCD sharing)
  const int bd   = bid % (BSZ * DIN);
  const int d = bd % DIN;
  const int b = bd / DIN;
  const int t   = threadIdx.x;              // 0..255
  const int s   = sq * 4 + (t >> 6);        // global state channel
  const int l64 = t & 63;
  const int pr  = l64 >> 3, pc = l64 & 7;   // 8x8 lane grid, 4x4 patch each
  const int K = Kp[0];
  const float dt = 1.0f / (float)K;
  const float Dc = 0.5f / (1.0f + expf(-diffraw[d]));
  const float A  = -log1pf(expf(Alog[d * DST + s]));
  const float dtDc = dt * Dc;
  const long col = (long)(b * DIN + d) * NTOK;
  const long gr0 = (long)b * NTOK;
  const int  c0  = pc * 4;

  // CT prefetch: issued now, consumed after the k-loop (~latency hidden)
  float4 cv[4];
#pragma unroll
  for (int i = 0; i < 4; ++i)
    cv[i] = *(const float4*)&CT[(long)s * MROWS + gr0 + (pr * 4 + i) * 32 + c0];

  float h[16], cA[16], g0[16], a2v[16];
#pragma unroll
  for (int i = 0; i < 4; ++i) {
    const int n = (pr * 4 + i) * 32 + c0;
    float4 xv = *(const float4*)&xT[col + n];
    float4 bv = *(const float4*)&BT[(long)s * MROWS + gr0 + n];
    uint2 dsw = *(const uint2*)&dsT[col + n];
    uint2 ddw = *(const uint2*)&ddT[col + n];
    float dsf[4] = { bf16_lo(dsw.x), bf16_hi(dsw.x), bf16_lo(dsw.y), bf16_hi(dsw.y) };
    float ddf[4] = { bf16_lo(ddw.x), bf16_hi(ddw.x), bf16_lo(ddw.y), bf16_hi(ddw.y) };
    float xa[4] = { xv.x, xv.y, xv.z, xv.w };
    float ba[4] = { bv.x, bv.y, bv.z, bv.w };
#pragma unroll
    for (int j = 0; j < 4; ++j) {
      const int e = i * 4 + j;
      float a1 = dt * dsf[j];
      float a2 = dtDc * ddf[j];
      float h0 = xa[j] * ba[j];
      h[e]   = h0;
      g0[e]  = a1 * h0;
      a2v[e] = a2;
      cA[e]  = fmaf(a1, A, 1.0f) - 4.0f * a2;
    }
  }

  const int lu = (l64 - 8) & 63, ld = (l64 + 8) & 63;
  const int ll = (l64 - 1) & 63, lrr = (l64 + 1) & 63;

  for (int k = 0; k < K; ++k) {
    float up[4], dn[4], lf[4], rt[4];
#pragma unroll
    for (int j = 0; j < 4; ++j) {
      up[j] = __shfl(h[12 + j], lu);        // lane above's bottom row
      dn[j] = __shfl(h[j], ld);             // lane below's top row
      lf[j] = __shfl(h[4 * j + 3], ll);     // left lane's right col
      rt[j] = __shfl(h[4 * j], lrr);        // right lane's left col
    }
#pragma unroll
    for (int j = 0; j < 4; ++j) {           // replicate-pad at grid edges
      up[j] = (pr == 0) ? h[j]          : up[j];
      dn[j] = (pr == 7) ? h[12 + j]     : dn[j];
      lf[j] = (pc == 0) ? h[4 * j]      : lf[j];
      rt[j] = (pc == 7) ? h[4 * j + 3]  : rt[j];
    }
    float hn[16];
#pragma unroll
    for (int i = 0; i < 4; ++i)
#pragma unroll
      for (int j = 0; j < 4; ++j) {
        const int e = i * 4 + j;
        float uv = (i == 0) ? up[j] : h[e - 4];
        float dv = (i == 3) ? dn[j] : h[e + 4];
        float lv = (j == 0) ? lf[i] : h[e - 1];
        float rv = (j == 3) ? rt[i] : h[e + 1];
        float S  = (uv + dv) + (lv + rv);
        hn[e] = fmaf(cA[e], h[e], fmaf(a2v[e], S, g0[e]));
      }
#pragma unroll
    for (int e = 0; e < 16; ++e) h[e] = hn[e];
  }

  // per-s partial y into LDS (wave index = s & 3)
  const int sw = t >> 6;
#pragma unroll
  for (int i = 0; i < 4; ++i) {
    const int n = (pr * 4 + i) * 32 + c0;
    float4 pv;
    pv.x = h[i * 4 + 0] * cv[i].x;
    pv.y = h[i * 4 + 1] * cv[i].y;
    pv.z = h[i * 4 + 2] * cv[i].z;
    pv.w = h[i * 4 + 3] * cv[i].w;
    *(float4*)&P[sw * 1024 + n] = pv;
  }
  __syncthreads();

  // reduce 4 partials; thread t owns points t, t+256, t+512, t+768
  unsigned short* yQ = (sq == 0) ? yQ0 : (sq == 1) ? yQ1 : (sq == 2) ? yQ2 : yQ3;
#pragma unroll
  for (int j = 0; j < 4; ++j) {
    const int n = t + j * 256;
    float sum = P[n] + P[1024 + n] + P[2048 + n] + P[3072 + n];
    yQ[col + n] = f32_to_bf16(sum);
  }
}

// ---------------------------------------------------------------------------
// Kernel 3: out(b,n,d) = yQ0+yQ1+yQ2+yQ3 + x*D, transposed via LDS tile.
// ---------------------------------------------------------------------------
__global__ __launch_bounds__(256) void untranspose_kernel(
    const unsigned short* __restrict__ yQ0, const unsigned short* __restrict__ yQ1,
    const unsigned short* __restrict__ yQ2, const unsigned short* __restrict__ yQ3,
    const float* __restrict__ xT, const float* __restrict__ Dparam,
    float* __restrict__ out)
{
  __shared__ float tile[32][33];
  const int n0 = blockIdx.x * 32;
  const int d0 = blockIdx.y * 32;
  const int b  = blockIdx.z;
  const int tx = threadIdx.x & 31, ty = threadIdx.x >> 5;
#pragma unroll
  for (int i = 0; i < 4; ++i) {
    int dd = d0 + ty + i * 8;
    long idx = (long)(b * DIN + dd) * NTOK + n0 + tx;
    float v0 = __uint_as_float((unsigned int)yQ0[idx] << 16);
    float v1 = __uint_as_float((unsigned int)yQ1[idx] << 16);
    float v2 = __uint_as_float((unsigned int)yQ2[idx] << 16);
    float v3 = __uint_as_float((unsigned int)yQ3[idx] << 16);
    tile[ty + i * 8][tx] = ((v0 + v1) + (v2 + v3)) + xT[idx] * Dparam[dd];
  }
  __syncthreads();
#pragma unroll
  for (int i = 0; i < 4; ++i) {
    int nn = n0 + ty + i * 8;
    out[(long)(b * NTOK + nn) * DIN + d0 + tx] = tile[tx][ty + i * 8];
  }
}

extern "C" void kernel_launch(void* const* d_in, const int* in_sizes, int n_in,
                              void* d_out, int out_size, void* d_ws, size_t ws_size,
                              hipStream_t stream) {
  const float* x     = (const float*)d_in[0];
  const float* Wdts  = (const float*)d_in[1];
  const float* bdts  = (const float*)d_in[2];
  const float* Wdtd  = (const float*)d_in[3];
  const float* bdtd  = (const float*)d_in[4];
  const float* WB    = (const float*)d_in[5];
  const float* WC    = (const float*)d_in[6];
  const float* Dpar  = (const float*)d_in[7];
  const float* Alog  = (const float*)d_in[8];
  const float* diffr = (const float*)d_in[9];
  const int*   Kst   = (const int*)d_in[10];

  // ws layout (~19.4 MB): BT | CT | xT | yQ0..yQ3 (bf16).  xb+Wb alias the yQ
  // region (dead until ssm writes yQ — stream-ordered).
  float* BT = (float*)d_ws;                        // [16][4096]
  float* CT = BT + (long)DST * MROWS;              // [16][4096]
  float* xT = CT + (long)DST * MROWS;
  unsigned short* yQ0 = (unsigned short*)(xT + NM);   // 4 x NM u16
  unsigned short* yQ1 = yQ0 + NM;
  unsigned short* yQ2 = yQ1 + NM;
  unsigned short* yQ3 = yQ2 + NM;
  unsigned short* xb  = yQ0;                          // alias (pre-ssm)
  unsigned short* Wb  = xb + NM;                      // 832*384 bf16

  // d_out scratch: bf16 delta planes between proj and ssm
  unsigned short* dsT = (unsigned short*)d_out;
  unsigned short* ddT = dsT + NM;

  prep_kernel<<<dim3(NTOK / 32, DIN / 32, BSZ + 1), dim3(256), 0, stream>>>(
      x, xT, xb, Wdts, Wdtd, WB, WC, Wb);

  proj_mfma_kernel<<<dim3(64 * 13), dim3(256), 0, stream>>>(
      xb, Wb, bdts, bdtd, dsT, ddT, BT, CT);

  ssm_kernel<<<dim3(BSZ * DIN * 4), dim3(256), 0, stream>>>(
      xT, dsT, ddT, BT, CT, Alog, diffr, Kst, yQ0, yQ1, yQ2, yQ3);

  untranspose_kernel<<<dim3(NTOK / 32, DIN / 32, BSZ), dim3(256), 0, stream>>>(
      yQ0, yQ1, yQ2, yQ3, xT, Dpar, (float*)d_out);
}

// Round 21
// 62.674 us; speedup vs baseline: 1.2472x; 1.0167x over previous
//
#include <hip/hip_runtime.h>
#include <hip/hip_bf16.h>

#define BSZ   4
#define NTOK  1024
#define DIN   384
#define DST   16
#define MROWS (BSZ * NTOK)     // 4096
#define KDIM  384
#define NM    (MROWS * DIN)    // 1572864 elements per plane

typedef __attribute__((ext_vector_type(8))) short bf16x8;
typedef __attribute__((ext_vector_type(4))) float f32x4;

__device__ __forceinline__ float softplus_f(float z) {
  return (z > 20.0f) ? z : log1pf(expf(z));
}

__device__ __forceinline__ unsigned short f32_to_bf16(float f) {
  unsigned int u = __float_as_uint(f);
  unsigned int rnd = 0x7fffu + ((u >> 16) & 1u);   // round-to-nearest-even
  return (unsigned short)((u + rnd) >> 16);
}

__device__ __forceinline__ float bf16_lo(unsigned int w) { return __uint_as_float(w << 16); }
__device__ __forceinline__ float bf16_hi(unsigned int w) { return __uint_as_float(w & 0xffff0000u); }

// ---------------------------------------------------------------------------
// Kernel 0 (fused prep): z<4 -> x (b,n,d) -> xT f32 + xb bf16;
//                        z==4 -> concat(Wdts|Wdtd|WB|WC|0) f32 -> bf16 Wb[832][384]
// ---------------------------------------------------------------------------
__global__ __launch_bounds__(256) void prep_kernel(
    const float* __restrict__ x, float* __restrict__ xT,
    unsigned short* __restrict__ xb,
    const float* __restrict__ Wdts, const float* __restrict__ Wdtd,
    const float* __restrict__ WB,   const float* __restrict__ WC,
    unsigned short* __restrict__ Wb)
{
  if (blockIdx.z == 4) {
    const int lin = blockIdx.y * 32 + blockIdx.x;    // 0..383, use 0..155
    if (lin >= 156) return;
    const int idx8 = (lin * 256 + threadIdx.x) * 8;
    const int row = idx8 / KDIM;
    const int k   = idx8 % KDIM;
    uint4 o = make_uint4(0u, 0u, 0u, 0u);
    if (row < 800) {
      const float* src;
      if (row < 384)      src = Wdts + (long)row * KDIM + k;
      else if (row < 768) src = Wdtd + (long)(row - 384) * KDIM + k;
      else if (row < 784) src = WB   + (long)(row - 768) * KDIM + k;
      else                src = WC   + (long)(row - 784) * KDIM + k;
      float4 v0 = *(const float4*)src;
      float4 v1 = *(const float4*)(src + 4);
      o.x = (unsigned int)f32_to_bf16(v0.x) | ((unsigned int)f32_to_bf16(v0.y) << 16);
      o.y = (unsigned int)f32_to_bf16(v0.z) | ((unsigned int)f32_to_bf16(v0.w) << 16);
      o.z = (unsigned int)f32_to_bf16(v1.x) | ((unsigned int)f32_to_bf16(v1.y) << 16);
      o.w = (unsigned int)f32_to_bf16(v1.z) | ((unsigned int)f32_to_bf16(v1.w) << 16);
    }
    *(uint4*)&Wb[idx8] = o;
    return;
  }
  __shared__ float tile[32][33];
  const int n0 = blockIdx.x * 32;
  const int d0 = blockIdx.y * 32;
  const int b  = blockIdx.z;
  const int tx = threadIdx.x & 31, ty = threadIdx.x >> 5;   // ty 0..7
#pragma unroll
  for (int i = 0; i < 4; ++i) {
    int nn = n0 + ty + i * 8;
    float v = x[(long)(b * NTOK + nn) * DIN + d0 + tx];
    tile[ty + i * 8][tx] = v;
    xb[(long)(b * NTOK + nn) * DIN + d0 + tx] = f32_to_bf16(v);
  }
  __syncthreads();
#pragma unroll
  for (int i = 0; i < 4; ++i) {
    int dd = d0 + ty + i * 8;
    xT[(long)(b * DIN + dd) * NTOK + n0 + tx] = tile[tx][ty + i * 8];
  }
}

// ---------------------------------------------------------------------------
// Kernel 1: full projection GEMM via bf16 MFMA (4096 x 832 x 384), BK=64,
// double-buffered LDS staged by global_load_lds width-16 (async DMA, no VGPR
// roundtrip — removes the PSTORE latency serialization of r16-r19).
// LDS dest LINEAR [64][64]; global source PRE-SWIZZLED slot^(row&7); frag
// reads apply the same XOR (both-sides-or-neither). Each 32-lane b128 read
// hits every bank exactly 4x = conflict-free.
//   bn<12 : delta cols -> softplus+clamp, bf16, LDS-transpose, d-major planes
//   bn==12: B/C cols -> f32 TRANSPOSED planes BT/CT[s][4096] (float4 stores)
// ---------------------------------------------------------------------------
#define AREAD(MAT, ROW, KO) \
  (*(const bf16x8*)&(MAT)[(ROW) * 64 + ((((KO) >> 3) ^ ((ROW) & 7)) << 3)])

__global__ __launch_bounds__(256) void proj_mfma_kernel(
    const unsigned short* __restrict__ xb,   // bf16 x, row-major [4096][384]
    const unsigned short* __restrict__ Wb,   // bf16 W, row-major [832][384]
    const float* __restrict__ bdts, const float* __restrict__ bdtd,
    unsigned short* __restrict__ dsT, unsigned short* __restrict__ ddT,
    float* __restrict__ BT, float* __restrict__ CT)
{
  __shared__ short smem_s[2][2][64 * 64];   // [buf][A|W][64 rows x 64 k] = 32768 B

  const int t    = threadIdx.x;
  const int bm   = blockIdx.x & 63;         // 64 row tiles
  const int bn   = blockIdx.x >> 6;         // 13 col tiles
  const int row0 = bm * 64;
  const int col0 = bn * 64;                 // 0..831
  const int bat  = row0 >> 10;
  const int n0   = row0 & 1023;

  const int l  = t & 63;
  const int w  = t >> 6;
  const int wr = (w >> 1) * 32;             // wave row base
  const int wc = (w & 1) * 32;              // wave col base
  const int lr = l & 15;
  const int lk = (l >> 4) * 8;              // k offset in frag (bf16)

  // staging geometry: slot sIdx in [0,512), 16B each; row = sIdx>>3,
  // phys slot-in-row = sIdx&7, LOGICAL k-slot = (sIdx&7)^(row&7).
  const int s0 = t,       r0 = s0 >> 3;
  const int s1 = 256 + t, r1 = s1 >> 3;
  const int j0 = ((s0 & 7) ^ (r0 & 7)) << 3;   // logical k offset (shorts)
  const int j1 = ((s1 & 7) ^ (r1 & 7)) << 3;
  const int wb0 = (t & 192) * 8;               // wave-uniform LDS short offset
  const int wb1 = (256 + (t & 192)) * 8;

#define STAGEM(LBASE, GSRC)                                                \
  {                                                                        \
    __builtin_amdgcn_global_load_lds(                                      \
        (const void*)((GSRC) + (long)r0 * KDIM + j0),                      \
        (void*)((LBASE) + wb0), 16, 0, 0);                                 \
    __builtin_amdgcn_global_load_lds(                                      \
        (const void*)((GSRC) + (long)r1 * KDIM + j1),                      \
        (void*)((LBASE) + wb1), 16, 0, 0);                                 \
  }

  f32x4 acc[2][2];
  const f32x4 zero = {0.f, 0.f, 0.f, 0.f};
  acc[0][0] = zero; acc[0][1] = zero; acc[1][0] = zero; acc[1][1] = zero;

  const unsigned short* Ag = xb + (long)row0 * KDIM;
  const unsigned short* Wg = Wb + (long)col0 * KDIM;

  STAGEM(smem_s[0][0], Ag);
  STAGEM(smem_s[0][1], Wg);

  for (int it = 0; it < 6; ++it) {
    const int cur = it & 1;
    __syncthreads();                        // vmcnt drained: buf[cur] ready
    if (it + 1 < 6) {                       // async DMA under the MFMAs
      const int k0n = (it + 1) * 64;
      STAGEM(smem_s[cur ^ 1][0], Ag + k0n);
      STAGEM(smem_s[cur ^ 1][1], Wg + k0n);
    }
    const short* Asm = smem_s[cur][0];
    const short* Wsm = smem_s[cur][1];
#pragma unroll
    for (int kh = 0; kh < 2; ++kh) {
      const int ko = kh * 32 + lk;
      bf16x8 a0 = AREAD(Asm, wr + lr, ko);
      bf16x8 a1 = AREAD(Asm, wr + 16 + lr, ko);
      bf16x8 b0 = AREAD(Wsm, wc + lr, ko);
      bf16x8 b1 = AREAD(Wsm, wc + 16 + lr, ko);
      acc[0][0] = __builtin_amdgcn_mfma_f32_16x16x32_bf16(a0, b0, acc[0][0], 0, 0, 0);
      acc[0][1] = __builtin_amdgcn_mfma_f32_16x16x32_bf16(a0, b1, acc[0][1], 0, 0, 0);
      acc[1][0] = __builtin_amdgcn_mfma_f32_16x16x32_bf16(a1, b0, acc[1][0], 0, 0, 0);
      acc[1][1] = __builtin_amdgcn_mfma_f32_16x16x32_bf16(a1, b1, acc[1][1], 0, 0, 0);
    }
  }
#undef STAGEM

  if (bn < 12) {
    const float* bias = (bn < 6) ? bdts : bdtd;
    unsigned short* plane = (bn < 6) ? dsT : ddT;
    const int dbase = (bn < 6) ? col0 : col0 - 384;
    const float bv0 = bias[dbase + wc + lr];
    const float bv1 = bias[dbase + wc + 16 + lr];
    __syncthreads();                        // frag reads done before smem reuse
    unsigned short* outl = (unsigned short*)smem_s;   // [64 d][72 n] u16
#pragma unroll
    for (int i = 0; i < 2; ++i)
#pragma unroll
      for (int j = 0; j < 2; ++j) {
        const float bb = j ? bv1 : bv0;
        const int cl = wc + j * 16 + lr;
#pragma unroll
        for (int q = 0; q < 4; ++q) {
          const int nl = wr + i * 16 + (l >> 4) * 4 + q;
          float dl = fminf(softplus_f(acc[i][j][q] + bb), 0.15f);
          outl[cl * 72 + nl] = f32_to_bf16(dl);
        }
      }
    __syncthreads();
    const int dl = t >> 2;
    const int seg = t & 3;
    uint4 w0 = *(const uint4*)&outl[dl * 72 + seg * 16];
    uint4 w1 = *(const uint4*)&outl[dl * 72 + seg * 16 + 8];
    long addr = (long)(bat * DIN + dbase + dl) * NTOK + n0 + seg * 16;
    *(uint4*)&plane[addr]     = w0;
    *(uint4*)&plane[addr + 8] = w1;
  } else {
    // B/C epilogue: transposed f32 planes, float4 per (i,j) fragment
#pragma unroll
    for (int i = 0; i < 2; ++i)
#pragma unroll
      for (int j = 0; j < 2; ++j) {
        const int cl = wc + j * 16 + lr;
        const int rowbase = row0 + wr + i * 16 + (l >> 4) * 4;
        if (cl < 16)       *(f32x4*)&BT[(long)cl * MROWS + rowbase] = acc[i][j];
        else if (cl < 32)  *(f32x4*)&CT[(long)(cl - 16) * MROWS + rowbase] = acc[i][j];
      }
  }
}

// ---------------------------------------------------------------------------
// Kernel 2: wave-parallel recurrence, QUARTER-SPLIT, sq-MAJOR grid
// (sq partners 1536 apart -> same XCD under bid%8 -> shared L2 for columns).
// 256 thr = 4 waves = 4 s-channels; lane owns a 4x4 f32 register patch;
// halo via __shfl; CT prefetched at START (consumed only after k-loop).
// NOTE: no 2nd launch_bounds arg (r9/r13: it force-caps VGPR -> spills).
// ---------------------------------------------------------------------------
__global__ __launch_bounds__(256) void ssm_kernel(
    const float* __restrict__ xT,
    const unsigned short* __restrict__ dsT,
    const unsigned short* __restrict__ ddT,
    const float* __restrict__ BT, const float* __restrict__ CT,
    const float* __restrict__ Alog,
    const float* __restrict__ diffraw, const int* __restrict__ Kp,
    unsigned short* __restrict__ yQ0, unsigned short* __restrict__ yQ1,
    unsigned short* __restrict__ yQ2, unsigned short* __restrict__ yQ3)
{
  __shared__ float P[4 * 1024];             // 16384 B partial plane
  const int bid  = blockIdx.x;
  const int sq   = bid / (BSZ * DIN);       // sq-major (XCD sharing)
  const int bd   = bid % (BSZ * DIN);
  const int d = bd % DIN;
  const int b = bd / DIN;
  const int t   = threadIdx.x;              // 0..255
  const int s   = sq * 4 + (t >> 6);        // global state channel
  const int l64 = t & 63;
  const int pr  = l64 >> 3, pc = l64 & 7;   // 8x8 lane grid, 4x4 patch each
  const int K = Kp[0];
  const float dt = 1.0f / (float)K;
  const float Dc = 0.5f / (1.0f + expf(-diffraw[d]));
  const float A  = -log1pf(expf(Alog[d * DST + s]));
  const float dtDc = dt * Dc;
  const long col = (long)(b * DIN + d) * NTOK;
  const long gr0 = (long)b * NTOK;
  const int  c0  = pc * 4;

  // CT prefetch: issued now, consumed after the k-loop (~latency hidden)
  float4 cv[4];
#pragma unroll
  for (int i = 0; i < 4; ++i)
    cv[i] = *(const float4*)&CT[(long)s * MROWS + gr0 + (pr * 4 + i) * 32 + c0];

  float h[16], cA[16], g0[16], a2v[16];
#pragma unroll
  for (int i = 0; i < 4; ++i) {
    const int n = (pr * 4 + i) * 32 + c0;
    float4 xv = *(const float4*)&xT[col + n];
    float4 bv = *(const float4*)&BT[(long)s * MROWS + gr0 + n];
    uint2 dsw = *(const uint2*)&dsT[col + n];
    uint2 ddw = *(const uint2*)&ddT[col + n];
    float dsf[4] = { bf16_lo(dsw.x), bf16_hi(dsw.x), bf16_lo(dsw.y), bf16_hi(dsw.y) };
    float ddf[4] = { bf16_lo(ddw.x), bf16_hi(ddw.x), bf16_lo(ddw.y), bf16_hi(ddw.y) };
    float xa[4] = { xv.x, xv.y, xv.z, xv.w };
    float ba[4] = { bv.x, bv.y, bv.z, bv.w };
#pragma unroll
    for (int j = 0; j < 4; ++j) {
      const int e = i * 4 + j;
      float a1 = dt * dsf[j];
      float a2 = dtDc * ddf[j];
      float h0 = xa[j] * ba[j];
      h[e]   = h0;
      g0[e]  = a1 * h0;
      a2v[e] = a2;
      cA[e]  = fmaf(a1, A, 1.0f) - 4.0f * a2;
    }
  }

  const int lu = (l64 - 8) & 63, ld = (l64 + 8) & 63;
  const int ll = (l64 - 1) & 63, lrr = (l64 + 1) & 63;

  for (int k = 0; k < K; ++k) {
    float up[4], dn[4], lf[4], rt[4];
#pragma unroll
    for (int j = 0; j < 4; ++j) {
      up[j] = __shfl(h[12 + j], lu);        // lane above's bottom row
      dn[j] = __shfl(h[j], ld);             // lane below's top row
      lf[j] = __shfl(h[4 * j + 3], ll);     // left lane's right col
      rt[j] = __shfl(h[4 * j], lrr);        // right lane's left col
    }
#pragma unroll
    for (int j = 0; j < 4; ++j) {           // replicate-pad at grid edges
      up[j] = (pr == 0) ? h[j]          : up[j];
      dn[j] = (pr == 7) ? h[12 + j]     : dn[j];
      lf[j] = (pc == 0) ? h[4 * j]      : lf[j];
      rt[j] = (pc == 7) ? h[4 * j + 3]  : rt[j];
    }
    float hn[16];
#pragma unroll
    for (int i = 0; i < 4; ++i)
#pragma unroll
      for (int j = 0; j < 4; ++j) {
        const int e = i * 4 + j;
        float uv = (i == 0) ? up[j] : h[e - 4];
        float dv = (i == 3) ? dn[j] : h[e + 4];
        float lv = (j == 0) ? lf[i] : h[e - 1];
        float rv = (j == 3) ? rt[i] : h[e + 1];
        float S  = (uv + dv) + (lv + rv);
        hn[e] = fmaf(cA[e], h[e], fmaf(a2v[e], S, g0[e]));
      }
#pragma unroll
    for (int e = 0; e < 16; ++e) h[e] = hn[e];
  }

  // per-s partial y into LDS (wave index = s & 3)
  const int sw = t >> 6;
#pragma unroll
  for (int i = 0; i < 4; ++i) {
    const int n = (pr * 4 + i) * 32 + c0;
    float4 pv;
    pv.x = h[i * 4 + 0] * cv[i].x;
    pv.y = h[i * 4 + 1] * cv[i].y;
    pv.z = h[i * 4 + 2] * cv[i].z;
    pv.w = h[i * 4 + 3] * cv[i].w;
    *(float4*)&P[sw * 1024 + n] = pv;
  }
  __syncthreads();

  // reduce 4 partials; thread t owns points t, t+256, t+512, t+768
  unsigned short* yQ = (sq == 0) ? yQ0 : (sq == 1) ? yQ1 : (sq == 2) ? yQ2 : yQ3;
#pragma unroll
  for (int j = 0; j < 4; ++j) {
    const int n = t + j * 256;
    float sum = P[n] + P[1024 + n] + P[2048 + n] + P[3072 + n];
    yQ[col + n] = f32_to_bf16(sum);
  }
}

// ---------------------------------------------------------------------------
// Kernel 3: out(b,n,d) = yQ0+yQ1+yQ2+yQ3 + x*D, transposed via LDS tile.
// ---------------------------------------------------------------------------
__global__ __launch_bounds__(256) void untranspose_kernel(
    const unsigned short* __restrict__ yQ0, const unsigned short* __restrict__ yQ1,
    const unsigned short* __restrict__ yQ2, const unsigned short* __restrict__ yQ3,
    const float* __restrict__ xT, const float* __restrict__ Dparam,
    float* __restrict__ out)
{
  __shared__ float tile[32][33];
  const int n0 = blockIdx.x * 32;
  const int d0 = blockIdx.y * 32;
  const int b  = blockIdx.z;
  const int tx = threadIdx.x & 31, ty = threadIdx.x >> 5;
#pragma unroll
  for (int i = 0; i < 4; ++i) {
    int dd = d0 + ty + i * 8;
    long idx = (long)(b * DIN + dd) * NTOK + n0 + tx;
    float v0 = __uint_as_float((unsigned int)yQ0[idx] << 16);
    float v1 = __uint_as_float((unsigned int)yQ1[idx] << 16);
    float v2 = __uint_as_float((unsigned int)yQ2[idx] << 16);
    float v3 = __uint_as_float((unsigned int)yQ3[idx] << 16);
    tile[ty + i * 8][tx] = ((v0 + v1) + (v2 + v3)) + xT[idx] * Dparam[dd];
  }
  __syncthreads();
#pragma unroll
  for (int i = 0; i < 4; ++i) {
    int nn = n0 + ty + i * 8;
    out[(long)(b * NTOK + nn) * DIN + d0 + tx] = tile[tx][ty + i * 8];
  }
}

extern "C" void kernel_launch(void* const* d_in, const int* in_sizes, int n_in,
                              void* d_out, int out_size, void* d_ws, size_t ws_size,
                              hipStream_t stream) {
  const float* x     = (const float*)d_in[0];
  const float* Wdts  = (const float*)d_in[1];
  const float* bdts  = (const float*)d_in[2];
  const float* Wdtd  = (const float*)d_in[3];
  const float* bdtd  = (const float*)d_in[4];
  const float* WB    = (const float*)d_in[5];
  const float* WC    = (const float*)d_in[6];
  const float* Dpar  = (const float*)d_in[7];
  const float* Alog  = (const float*)d_in[8];
  const float* diffr = (const float*)d_in[9];
  const int*   Kst   = (const int*)d_in[10];

  // ws layout (~19.4 MB): BT | CT | xT | yQ0..yQ3 (bf16).  xb+Wb alias the yQ
  // region (dead until ssm writes yQ — stream-ordered).
  float* BT = (float*)d_ws;                        // [16][4096]
  float* CT = BT + (long)DST * MROWS;              // [16][4096]
  float* xT = CT + (long)DST * MROWS;
  unsigned short* yQ0 = (unsigned short*)(xT + NM);   // 4 x NM u16
  unsigned short* yQ1 = yQ0 + NM;
  unsigned short* yQ2 = yQ1 + NM;
  unsigned short* yQ3 = yQ2 + NM;
  unsigned short* xb  = yQ0;                          // alias (pre-ssm)
  unsigned short* Wb  = xb + NM;                      // 832*384 bf16

  // d_out scratch: bf16 delta planes between proj and ssm
  unsigned short* dsT = (unsigned short*)d_out;
  unsigned short* ddT = dsT + NM;

  prep_kernel<<<dim3(NTOK / 32, DIN / 32, BSZ + 1), dim3(256), 0, stream>>>(
      x, xT, xb, Wdts, Wdtd, WB, WC, Wb);

  proj_mfma_kernel<<<dim3(64 * 13), dim3(256), 0, stream>>>(
      xb, Wb, bdts, bdtd, dsT, ddT, BT, CT);

  ssm_kernel<<<dim3(BSZ * DIN * 4), dim3(256), 0, stream>>>(
      xT, dsT, ddT, BT, CT, Alog, diffr, Kst, yQ0, yQ1, yQ2, yQ3);

  untranspose_kernel<<<dim3(NTOK / 32, DIN / 32, BSZ), dim3(256), 0, stream>>>(
      yQ0, yQ1, yQ2, yQ3, xT, Dpar, (float*)d_out);
}